// Round 1
// baseline (153.074 us; speedup 1.0000x reference)
//
#include <hip/hip_runtime.h>
#include <hip/hip_bf16.h>

// PointPillarScatter: out[1, C, NY, NX] (fp32), zero except
// out[c, y, x] = pillar_features[c, p] for each pillar p with coords (z=0, y, x).
// C=64, NX=NY=1024, P=100000. Inputs:
//   d_in[0]: pillar_features float32 [C, P]
//   d_in[1]: coords int32 [1, P, 3]  (z, y, x)

constexpr int C_CH   = 64;
constexpr int NX_G   = 1024;
constexpr int NY_G   = 1024;
constexpr int NCELLS = NX_G * NY_G;

__global__ void pp_scatter_kernel(const float* __restrict__ pf,
                                  const int* __restrict__ coords,
                                  float* __restrict__ out,
                                  int P) {
    int t = blockIdx.x * blockDim.x + threadIdx.x;
    int total = C_CH * P;
    if (t >= total) return;
    int c = t / P;          // channel
    int p = t - c * P;      // pillar
    // flat BEV index = z + y*NX + x
    int z = coords[3 * p + 0];
    int y = coords[3 * p + 1];
    int x = coords[3 * p + 2];
    int idx = z + y * NX_G + x;
    // pf is [C, P] row-major, t == c*P + p -> coalesced read
    out[(size_t)c * NCELLS + idx] = pf[t];
}

extern "C" void kernel_launch(void* const* d_in, const int* in_sizes, int n_in,
                              void* d_out, int out_size, void* d_ws, size_t ws_size,
                              hipStream_t stream) {
    const float* pf     = (const float*)d_in[0];
    const int*   coords = (const int*)d_in[1];
    float*       out    = (float*)d_out;

    const int P = in_sizes[0] / C_CH;  // 100000

    // Zero-fill the dense grid every call (harness poisons once, never re-poisons).
    hipMemsetAsync(d_out, 0, (size_t)out_size * sizeof(float), stream);

    const int total   = C_CH * P;
    const int block   = 256;
    const int grid    = (total + block - 1) / block;
    pp_scatter_kernel<<<grid, block, 0, stream>>>(pf, coords, out, P);
}

// Round 2
// 98.917 us; speedup vs baseline: 1.5475x; 1.5475x over previous
//
#include <hip/hip_runtime.h>
#include <hip/hip_bf16.h>

// PointPillarScatter: out[1, C, NY, NX] (fp32), zero except
// out[c, y, x] = pillar_features[c, p] for pillar p at (z=0, y, x).
// C=64, NX=NY=1024, P=100000.
//   d_in[0]: pillar_features float32 [C, P]
//   d_in[1]: coords int32 [1, P, 3] (z, y, x)
//
// Strategy: inverse map (cell -> pillar id) in d_ws, then a single
// full-coverage gather pass that writes every output element exactly once,
// coalesced (fuses the zero-fill with the scatter).

constexpr int C_CH   = 64;
constexpr int NX_G   = 1024;
constexpr int NY_G   = 1024;
constexpr int NCELLS = NX_G * NY_G;

__global__ void pp_build_map(const int* __restrict__ coords,
                             int* __restrict__ map, int P) {
    int p = blockIdx.x * blockDim.x + threadIdx.x;
    if (p >= P) return;
    int z = coords[3 * p + 0];
    int y = coords[3 * p + 1];
    int x = coords[3 * p + 2];
    map[z + y * NX_G + x] = p;
}

__global__ void pp_gather(const float* __restrict__ pf,
                          const int* __restrict__ map,
                          float4* __restrict__ out, int P) {
    int t = blockIdx.x * blockDim.x + threadIdx.x;  // quad-cell id, NCELLS/4 total
    const int4 pid = reinterpret_cast<const int4*>(map)[t];
#pragma unroll 4
    for (int c = 0; c < C_CH; ++c) {
        const float* __restrict__ pfc = pf + (size_t)c * P;
        float4 v;
        v.x = (pid.x >= 0) ? pfc[pid.x] : 0.0f;
        v.y = (pid.y >= 0) ? pfc[pid.y] : 0.0f;
        v.z = (pid.z >= 0) ? pfc[pid.z] : 0.0f;
        v.w = (pid.w >= 0) ? pfc[pid.w] : 0.0f;
        out[(size_t)c * (NCELLS / 4) + t] = v;
    }
}

extern "C" void kernel_launch(void* const* d_in, const int* in_sizes, int n_in,
                              void* d_out, int out_size, void* d_ws, size_t ws_size,
                              hipStream_t stream) {
    const float* pf     = (const float*)d_in[0];
    const int*   coords = (const int*)d_in[1];
    float4*      out    = (float4*)d_out;
    int*         map    = (int*)d_ws;  // NCELLS ints = 4 MiB

    const int P = in_sizes[0] / C_CH;  // 100000

    // -1 sentinel everywhere (0xFFFFFFFF == -1).
    hipMemsetAsync(map, 0xFF, (size_t)NCELLS * sizeof(int), stream);

    pp_build_map<<<(P + 255) / 256, 256, 0, stream>>>(coords, map, P);

    const int quads = NCELLS / 4;                  // 262144 threads
    pp_gather<<<quads / 256, 256, 0, stream>>>(pf, map, out, P);
}

// Round 3
// 98.359 us; speedup vs baseline: 1.5563x; 1.0057x over previous
//
#include <hip/hip_runtime.h>
#include <hip/hip_bf16.h>

// PointPillarScatter: out[1, C, NY, NX] (fp32), zero except
// out[c, y, x] = pillar_features[c, p] for pillar p at (z=0, y, x).
// C=64, NX=NY=1024, P=100000.
//   d_in[0]: pillar_features float32 [C, P]
//   d_in[1]: coords int32 [1, P, 3] (z, y, x)
//
// Inverse-map + full-coverage gather (each output element written exactly
// once, coalesced). Round 3 change: custom vectorized fill kernel for the
// 4 MiB map — hipMemsetAsync's fillBufferAligned ran at 26 GB/s (~100 µs).

constexpr int C_CH   = 64;
constexpr int NX_G   = 1024;
constexpr int NY_G   = 1024;
constexpr int NCELLS = NX_G * NY_G;

__global__ void pp_fill_map(int4* __restrict__ map) {
    // NCELLS/4 = 262144 int4 stores; grid-stride not needed, launch exact.
    int t = blockIdx.x * blockDim.x + threadIdx.x;
    map[t] = make_int4(-1, -1, -1, -1);
}

__global__ void pp_build_map(const int* __restrict__ coords,
                             int* __restrict__ map, int P) {
    int p = blockIdx.x * blockDim.x + threadIdx.x;
    if (p >= P) return;
    int z = coords[3 * p + 0];
    int y = coords[3 * p + 1];
    int x = coords[3 * p + 2];
    map[z + y * NX_G + x] = p;
}

__global__ void pp_gather(const float* __restrict__ pf,
                          const int* __restrict__ map,
                          float4* __restrict__ out, int P) {
    int t = blockIdx.x * blockDim.x + threadIdx.x;  // quad-cell id
    const int4 pid = reinterpret_cast<const int4*>(map)[t];
#pragma unroll 4
    for (int c = 0; c < C_CH; ++c) {
        const float* __restrict__ pfc = pf + (size_t)c * P;
        float4 v;
        v.x = (pid.x >= 0) ? pfc[pid.x] : 0.0f;
        v.y = (pid.y >= 0) ? pfc[pid.y] : 0.0f;
        v.z = (pid.z >= 0) ? pfc[pid.z] : 0.0f;
        v.w = (pid.w >= 0) ? pfc[pid.w] : 0.0f;
        out[(size_t)c * (NCELLS / 4) + t] = v;
    }
}

extern "C" void kernel_launch(void* const* d_in, const int* in_sizes, int n_in,
                              void* d_out, int out_size, void* d_ws, size_t ws_size,
                              hipStream_t stream) {
    const float* pf     = (const float*)d_in[0];
    const int*   coords = (const int*)d_in[1];
    float4*      out    = (float4*)d_out;
    int*         map    = (int*)d_ws;  // NCELLS ints = 4 MiB

    const int P = in_sizes[0] / C_CH;  // 100000

    const int quads = NCELLS / 4;  // 262144

    pp_fill_map<<<quads / 256, 256, 0, stream>>>((int4*)map);
    pp_build_map<<<(P + 255) / 256, 256, 0, stream>>>(coords, map, P);
    pp_gather<<<quads / 256, 256, 0, stream>>>(pf, map, out, P);
}

// Round 4
// 74.756 us; speedup vs baseline: 2.0477x; 1.3157x over previous
//
#include <hip/hip_runtime.h>
#include <hip/hip_bf16.h>

// PointPillarScatter: out[1, C, NY, NX] (fp32), zero except
// out[c, y, x] = pillar_features[c, p] for pillar p at (z=0, y, x).
// C=64, NX=NY=1024, P=100000.
//   d_in[0]: pillar_features float32 [C, P]
//   d_in[1]: coords int32 [1, P, 3] (z, y, x)
//
// Inverse-map + full-coverage gather. Round 4: split the 64-channel serial
// loop across threads (4 channels/thread) -> 16x more waves, short
// independent load chains; nontemporal float4 stores for the 268 MB
// write-once output.

constexpr int C_CH   = 64;
constexpr int NX_G   = 1024;
constexpr int NY_G   = 1024;
constexpr int NCELLS = NX_G * NY_G;
constexpr int QUADS  = NCELLS / 4;      // 262144 = 2^18
constexpr int CPT    = 4;               // channels per thread
constexpr int GROUPS = C_CH / CPT;      // 16

typedef __attribute__((ext_vector_type(4))) float f32x4;

__global__ void pp_fill_map(int4* __restrict__ map) {
    int t = blockIdx.x * blockDim.x + threadIdx.x;
    map[t] = make_int4(-1, -1, -1, -1);
}

__global__ void pp_build_map(const int* __restrict__ coords,
                             int* __restrict__ map, int P) {
    int p = blockIdx.x * blockDim.x + threadIdx.x;
    if (p >= P) return;
    int z = coords[3 * p + 0];
    int y = coords[3 * p + 1];
    int x = coords[3 * p + 2];
    map[z + y * NX_G + x] = p;
}

__global__ void pp_gather(const float* __restrict__ pf,
                          const int* __restrict__ map,
                          float* __restrict__ out, int P) {
    int t = blockIdx.x * blockDim.x + threadIdx.x;  // [0, GROUPS*QUADS)
    int q = t & (QUADS - 1);    // quad-cell id -> coalesced map load + store
    int g = t >> 18;            // channel group
    const int4 pid = reinterpret_cast<const int4*>(map)[q];
    const int cbase = g * CPT;
#pragma unroll
    for (int i = 0; i < CPT; ++i) {
        const float* __restrict__ pfc = pf + (size_t)(cbase + i) * P;
        f32x4 v;
        v.x = (pid.x >= 0) ? pfc[pid.x] : 0.0f;
        v.y = (pid.y >= 0) ? pfc[pid.y] : 0.0f;
        v.z = (pid.z >= 0) ? pfc[pid.z] : 0.0f;
        v.w = (pid.w >= 0) ? pfc[pid.w] : 0.0f;
        f32x4* dst = reinterpret_cast<f32x4*>(out + (size_t)(cbase + i) * NCELLS) + q;
        __builtin_nontemporal_store(v, dst);
    }
}

extern "C" void kernel_launch(void* const* d_in, const int* in_sizes, int n_in,
                              void* d_out, int out_size, void* d_ws, size_t ws_size,
                              hipStream_t stream) {
    const float* pf     = (const float*)d_in[0];
    const int*   coords = (const int*)d_in[1];
    float*       out    = (float*)d_out;
    int*         map    = (int*)d_ws;  // NCELLS ints = 4 MiB

    const int P = in_sizes[0] / C_CH;  // 100000

    pp_fill_map<<<QUADS / 256, 256, 0, stream>>>((int4*)map);
    pp_build_map<<<(P + 255) / 256, 256, 0, stream>>>(coords, map, P);

    const int threads = GROUPS * QUADS;  // 4,194,304
    pp_gather<<<threads / 256, 256, 0, stream>>>(pf, map, out, P);
}